// Round 1
// baseline (513.086 us; speedup 1.0000x reference)
//
#include <hip/hip_runtime.h>
#include <hip/hip_bf16.h>

// retina_polar2: log-polar glimpse sampling + 10x10 avg-pool
// x:        [64, 3, 512, 512] f32
// l_t_prev: [64, 2]           f32
// grid_2d:  [320, 640, 2]     f32  (gx, gy)
// out:      [64, 3, 32, 64]   f32

#define B_    64
#define C_    3
#define HI_   512
#define WI_   512
#define HOUT_ 32
#define WOUT_ 64
#define UFR_  10
#define UFT_  10
#define HUP_  (HOUT_ * UFR_)   // 320
#define WUP_  (WOUT_ * UFT_)   // 640
#define BLK_  320              // threads per block (5 waves)

__global__ __launch_bounds__(BLK_) void retina_polar_kernel(
    const float* __restrict__ x,
    const float* __restrict__ lt,
    const float* __restrict__ grid,
    float* __restrict__ out)
{
    const int bid = blockIdx.x;
    const int b   = bid >> 5;        // / HOUT_ (32)
    const int ho  = bid & 31;        // % HOUT_
    const int tid = threadIdx.x;

    __shared__ float acc[C_][WOUT_]; // 3*64 floats

    for (int i = tid; i < C_ * WOUT_; i += BLK_)
        acc[i >> 6][i & 63] = 0.0f;
    __syncthreads();

    const float lx = lt[b * 2 + 0];
    const float ly = lt[b * 2 + 1];
    const float* __restrict__ xb = x + (size_t)b * C_ * HI_ * WI_;

    #pragma unroll
    for (int w2 = 0; w2 < 2; ++w2) {
        const int wu = tid + w2 * BLK_;          // theta column in [0,640)
        const int wo = wu / UFT_;                // output column
        float s0 = 0.f, s1 = 0.f, s2 = 0.f;

        #pragma unroll
        for (int rr = 0; rr < UFR_; ++rr) {
            const int hu = ho * UFR_ + rr;
            // grid load as float2 (coalesced, 8B/lane)
            const float2 g = *reinterpret_cast<const float2*>(
                grid + ((size_t)hu * WUP_ + wu) * 2);
            const float gx = g.x + lx;
            const float gy = g.y + ly;

            // unnormalize (align_corners=False), border clamp
            float ix = ((gx + 1.0f) * (float)WI_ - 1.0f) * 0.5f;
            float iy = ((gy + 1.0f) * (float)HI_ - 1.0f) * 0.5f;
            ix = fminf(fmaxf(ix, 0.0f), (float)(WI_ - 1));
            iy = fminf(fmaxf(iy, 0.0f), (float)(HI_ - 1));

            const float x0f = floorf(ix);
            const float y0f = floorf(iy);
            const float wx = ix - x0f;
            const float wy = iy - y0f;
            const int x0 = (int)x0f;
            const int y0 = (int)y0f;
            const int x1 = min(x0 + 1, WI_ - 1);
            const int y1 = min(y0 + 1, HI_ - 1);

            const int a00 = y0 * WI_ + x0;
            const int a01 = y0 * WI_ + x1;
            const int a10 = y1 * WI_ + x0;
            const int a11 = y1 * WI_ + x1;

            const float w11 = wx * wy;
            const float w10 = wy - w11;          // (1-wx)*wy
            const float w01 = wx - w11;          // wx*(1-wy)
            const float w00 = 1.0f - wx - wy + w11;

            const float* __restrict__ xc0 = xb;
            const float* __restrict__ xc1 = xb + (size_t)HI_ * WI_;
            const float* __restrict__ xc2 = xb + (size_t)2 * HI_ * WI_;

            s0 += xc0[a00] * w00 + xc0[a01] * w01 + xc0[a10] * w10 + xc0[a11] * w11;
            s1 += xc1[a00] * w00 + xc1[a01] * w01 + xc1[a10] * w10 + xc1[a11] * w11;
            s2 += xc2[a00] * w00 + xc2[a01] * w01 + xc2[a10] * w10 + xc2[a11] * w11;
        }

        atomicAdd(&acc[0][wo], s0);
        atomicAdd(&acc[1][wo], s1);
        atomicAdd(&acc[2][wo], s2);
    }
    __syncthreads();

    // write out [b, c, ho, wo], scaled by 1/100
    for (int i = tid; i < C_ * WOUT_; i += BLK_) {
        const int c  = i >> 6;
        const int wo = i & 63;
        out[(((size_t)b * C_ + c) * HOUT_ + ho) * WOUT_ + wo] =
            acc[c][wo] * 0.01f;
    }
}

extern "C" void kernel_launch(void* const* d_in, const int* in_sizes, int n_in,
                              void* d_out, int out_size, void* d_ws, size_t ws_size,
                              hipStream_t stream)
{
    const float* x    = (const float*)d_in[0];
    const float* lt   = (const float*)d_in[1];
    const float* grid = (const float*)d_in[2];
    float* out        = (float*)d_out;

    retina_polar_kernel<<<dim3(B_ * HOUT_), dim3(BLK_), 0, stream>>>(x, lt, grid, out);
}

// Round 2
// 230.300 us; speedup vs baseline: 2.2279x; 2.2279x over previous
//
#include <hip/hip_runtime.h>
#include <hip/hip_bf16.h>

// retina_polar2: log-polar glimpse sampling + 10x10 avg-pool
// x:        [64, 3, 512, 512] f32
// l_t_prev: [64, 2]           f32
// grid_2d:  [320, 640, 2]     f32  (gx, gy)
// out:      [64, 3, 32, 64]   f32
//
// Latency-bound gather kernel. Strategy: per-thread explicit register
// batching (40 independent global loads in flight per channel) + small
// blocks for occupancy. Block = (b, ho, theta-half), 320 threads, one
// theta column per thread, 10 radial sub-samples batched in registers.

#define B_    64
#define C_    3
#define HI_   512
#define WI_   512
#define HOUT_ 32
#define WOUT_ 64
#define UFR_  10
#define UFT_  10
#define WUP_  (WOUT_ * UFT_)   // 640
#define BLK_  320              // 5 waves

__global__ __launch_bounds__(BLK_) void retina_polar_kernel(
    const float* __restrict__ x,
    const float* __restrict__ lt,
    const float* __restrict__ grid,
    float* __restrict__ out)
{
    const int bid = blockIdx.x;
    const int b   = bid >> 6;          // / (HOUT_*2)
    const int ho  = (bid >> 1) & 31;
    const int seg = bid & 1;           // theta half: columns [seg*320, seg*320+320)
    const int tid = threadIdx.x;
    const int wu  = seg * BLK_ + tid;  // theta column

    __shared__ float acc[C_][32];      // 32 output columns per block

    if (tid < C_ * 32) acc[tid >> 5][tid & 31] = 0.0f;
    __syncthreads();

    const float lx = lt[b * 2 + 0];
    const float ly = lt[b * 2 + 1];
    const float* __restrict__ xb = x + (size_t)b * C_ * HI_ * WI_;

    // ---- phase 1: coordinates for all 10 radial sub-samples ----
    int   a00[UFR_];   // base gather offset (elements)
    int   dd [UFR_];   // dx1 | (dy1<<9):  a01=a00+(d&1), a10=a00+(d&512), a11=a00+d
    float wxv[UFR_], wyv[UFR_];

    const int hu0 = ho * UFR_;
    #pragma unroll
    for (int rr = 0; rr < UFR_; ++rr) {
        const float2 g = *reinterpret_cast<const float2*>(
            grid + ((size_t)(hu0 + rr) * WUP_ + wu) * 2);
        float ix = ((g.x + lx + 1.0f) * (float)WI_ - 1.0f) * 0.5f;
        float iy = ((g.y + ly + 1.0f) * (float)HI_ - 1.0f) * 0.5f;
        ix = fminf(fmaxf(ix, 0.0f), (float)(WI_ - 1));
        iy = fminf(fmaxf(iy, 0.0f), (float)(HI_ - 1));
        const float x0f = floorf(ix);
        const float y0f = floorf(iy);
        const int x0 = (int)x0f;
        const int y0 = (int)y0f;
        const int dx1 = min(x0 + 1, WI_ - 1) - x0;   // 0 or 1
        const int dy1 = min(y0 + 1, HI_ - 1) - y0;   // 0 or 1
        a00[rr] = y0 * WI_ + x0;
        dd [rr] = dx1 | (dy1 << 9);                  // dy1<<9 == dy1*WI_
        wxv[rr] = ix - x0f;
        wyv[rr] = iy - y0f;
    }

    // ---- phase 2: per-channel batched gathers (40 loads in flight) ----
    float s[C_];
    #pragma unroll
    for (int c = 0; c < C_; ++c) {
        const float* __restrict__ xc = xb + (size_t)c * HI_ * WI_;
        float v00[UFR_], v01[UFR_], v10[UFR_], v11[UFR_];
        #pragma unroll
        for (int rr = 0; rr < UFR_; ++rr) {
            const int A = a00[rr];
            const int d = dd[rr];
            v00[rr] = xc[A];
            v01[rr] = xc[A + (d & 1)];
            v10[rr] = xc[A + (d & 512)];
            v11[rr] = xc[A + d];
        }
        float a = 0.0f;
        #pragma unroll
        for (int rr = 0; rr < UFR_; ++rr) {
            const float w11 = wxv[rr] * wyv[rr];
            const float w10 = wyv[rr] - w11;
            const float w01 = wxv[rr] - w11;
            const float w00 = 1.0f - wxv[rr] - wyv[rr] + w11;
            a += v00[rr] * w00 + v01[rr] * w01 + v10[rr] * w10 + v11[rr] * w11;
        }
        s[c] = a;
    }

    // ---- phase 3: pool reduction (10 theta columns -> 1 output col) ----
    const int wo_local = tid / UFT_;   // 0..31
    atomicAdd(&acc[0][wo_local], s[0]);
    atomicAdd(&acc[1][wo_local], s[1]);
    atomicAdd(&acc[2][wo_local], s[2]);
    __syncthreads();

    if (tid < C_ * 32) {
        const int c  = tid >> 5;
        const int wl = tid & 31;
        out[(((size_t)b * C_ + c) * HOUT_ + ho) * WOUT_ + seg * 32 + wl] =
            acc[c][wl] * 0.01f;
    }
}

extern "C" void kernel_launch(void* const* d_in, const int* in_sizes, int n_in,
                              void* d_out, int out_size, void* d_ws, size_t ws_size,
                              hipStream_t stream)
{
    const float* x    = (const float*)d_in[0];
    const float* lt   = (const float*)d_in[1];
    const float* grid = (const float*)d_in[2];
    float* out        = (float*)d_out;

    retina_polar_kernel<<<dim3(B_ * HOUT_ * 2), dim3(BLK_), 0, stream>>>(x, lt, grid, out);
}

// Round 3
// 213.912 us; speedup vs baseline: 2.3986x; 1.0766x over previous
//
#include <hip/hip_runtime.h>
#include <hip/hip_bf16.h>

// retina_polar2: log-polar glimpse sampling + 10x10 avg-pool
// x:        [64, 3, 512, 512] f32
// l_t_prev: [64, 2]           f32
// grid_2d:  [320, 640, 2]     f32  (gx, gy)
// out:      [64, 3, 32, 64]   f32
//
// Latency/imbalance-bound gather. Strategy: homogeneous blocks.
// Block = (b, 80-theta wedge, radial-half). Each thread owns one theta
// column and 4 pool windows spread uniformly over the radial range, so
// every block has an identical inner/outer radius mix. 1024 equal blocks
// x 5 waves, VGPR-capped for 4 blocks/CU -> whole grid resident at once.

#define B_    64
#define C_    3
#define HI_   512
#define WI_   512
#define HOUT_ 32
#define WOUT_ 64
#define UFR_  10
#define UFT_  10
#define WUP_  (WOUT_ * UFT_)   // 640
#define WEDGE_ 80              // theta columns per block (8 pool windows)
#define BLK_  320              // 80 theta x 4 radial groups

__global__ __launch_bounds__(BLK_, 5) void retina_polar_kernel(
    const float* __restrict__ x,
    const float* __restrict__ lt,
    const float* __restrict__ grid,
    float* __restrict__ out)
{
    const int bid   = blockIdx.x;
    const int b     = bid >> 4;         // / 16
    const int wedge = (bid >> 1) & 7;   // 8 wedges
    const int h     = bid & 1;          // radial-window parity half
    const int tid   = threadIdx.x;
    const int tl    = tid % WEDGE_;     // theta within wedge
    const int rg    = tid / WEDGE_;     // 0..3
    const int wu    = wedge * WEDGE_ + tl;
    const int wol   = tl / UFT_;        // 0..7 local output column

    __shared__ float acc[C_][16][8];    // [c][window slot][wol]

    for (int i = tid; i < C_ * 16 * 8; i += BLK_)
        ((float*)acc)[i] = 0.0f;
    __syncthreads();

    const float lx = lt[b * 2 + 0];
    const float ly = lt[b * 2 + 1];
    const float* __restrict__ xb = x + (size_t)b * C_ * HI_ * WI_;

    #pragma unroll
    for (int k = 0; k < 4; ++k) {
        const int slot = rg + 4 * k;        // 0..15
        const int w    = h + 2 * slot;      // global window / ho, 0..31
        const int hu0  = w * UFR_;

        // ---- coordinates for the window's 10 radial rows ----
        int   a00[UFR_];
        int   dd [UFR_];   // dx1 | dy1<<9 : a01=+(d&1), a10=+(d&512), a11=+d
        float wxv[UFR_], wyv[UFR_];
        #pragma unroll
        for (int rr = 0; rr < UFR_; ++rr) {
            const float2 g = *reinterpret_cast<const float2*>(
                grid + ((size_t)(hu0 + rr) * WUP_ + wu) * 2);
            float ix = ((g.x + lx + 1.0f) * (float)WI_ - 1.0f) * 0.5f;
            float iy = ((g.y + ly + 1.0f) * (float)HI_ - 1.0f) * 0.5f;
            ix = fminf(fmaxf(ix, 0.0f), (float)(WI_ - 1));
            iy = fminf(fmaxf(iy, 0.0f), (float)(HI_ - 1));
            const float x0f = floorf(ix);
            const float y0f = floorf(iy);
            const int x0 = (int)x0f;
            const int y0 = (int)y0f;
            const int dx1 = min(x0 + 1, WI_ - 1) - x0;
            const int dy1 = min(y0 + 1, HI_ - 1) - y0;
            a00[rr] = y0 * WI_ + x0;
            dd [rr] = dx1 | (dy1 << 9);
            wxv[rr] = ix - x0f;
            wyv[rr] = iy - y0f;
        }

        // ---- per-channel batched gathers (40 independent loads) ----
        float s[C_];
        #pragma unroll
        for (int c = 0; c < C_; ++c) {
            const float* __restrict__ xc = xb + (size_t)c * HI_ * WI_;
            float v00[UFR_], v01[UFR_], v10[UFR_], v11[UFR_];
            #pragma unroll
            for (int rr = 0; rr < UFR_; ++rr) {
                const int A = a00[rr];
                const int d = dd[rr];
                v00[rr] = xc[A];
                v01[rr] = xc[A + (d & 1)];
                v10[rr] = xc[A + (d & 512)];
                v11[rr] = xc[A + d];
            }
            float a = 0.0f;
            #pragma unroll
            for (int rr = 0; rr < UFR_; ++rr) {
                const float w11 = wxv[rr] * wyv[rr];
                const float w10 = wyv[rr] - w11;
                const float w01 = wxv[rr] - w11;
                const float w00 = 1.0f - wxv[rr] - wyv[rr] + w11;
                a += v00[rr] * w00 + v01[rr] * w01 + v10[rr] * w10 + v11[rr] * w11;
            }
            s[c] = a;
        }

        atomicAdd(&acc[0][slot][wol], s[0]);
        atomicAdd(&acc[1][slot][wol], s[1]);
        atomicAdd(&acc[2][slot][wol], s[2]);
    }
    __syncthreads();

    // ---- write out: 3 * 16 slots * 8 cols = 384 values ----
    for (int i = tid; i < C_ * 16 * 8; i += BLK_) {
        const int c    = i >> 7;
        const int rem  = i & 127;
        const int slot = rem >> 3;
        const int wl   = rem & 7;
        const int w    = h + 2 * slot;
        out[(((size_t)b * C_ + c) * HOUT_ + w) * WOUT_ + wedge * 8 + wl] =
            acc[c][slot][wl] * 0.01f;
    }
}

extern "C" void kernel_launch(void* const* d_in, const int* in_sizes, int n_in,
                              void* d_out, int out_size, void* d_ws, size_t ws_size,
                              hipStream_t stream)
{
    const float* x    = (const float*)d_in[0];
    const float* lt   = (const float*)d_in[1];
    const float* grid = (const float*)d_in[2];
    float* out        = (float*)d_out;

    retina_polar_kernel<<<dim3(B_ * 8 * 2), dim3(BLK_), 0, stream>>>(x, lt, grid, out);
}

// Round 4
// 206.051 us; speedup vs baseline: 2.4901x; 1.0381x over previous
//
#include <hip/hip_runtime.h>
#include <hip/hip_bf16.h>

// retina_polar2: log-polar glimpse sampling + 10x10 avg-pool
// x:        [64, 3, 512, 512] f32
// l_t_prev: [64, 2]           f32
// grid_2d:  [320, 640, 2]     f32  (gx, gy)
// out:      [64, 3, 32, 64]   f32
//
// Latency-bound gather. Geometry (round 3): block = (b, 80-theta wedge,
// radial parity), 4 radial groups x 4 sequential windows per thread ->
// every block has an identical inner/outer radius mix (balanced).
// Round-4 fix: k-loop NOT unrolled (one window's register arrays live at
// a time -> no scratch spill), packed tap offsets (a00|dx<<18|dy<<19).

#define B_    64
#define C_    3
#define HI_   512
#define WI_   512
#define HOUT_ 32
#define WOUT_ 64
#define UFR_  10
#define UFT_  10
#define WUP_  (WOUT_ * UFT_)   // 640
#define WEDGE_ 80
#define BLK_  320

__global__ __launch_bounds__(BLK_) void retina_polar_kernel(
    const float* __restrict__ x,
    const float* __restrict__ lt,
    const float* __restrict__ grid,
    float* __restrict__ out)
{
    const int bid   = blockIdx.x;
    const int b     = bid >> 4;
    const int wedge = (bid >> 1) & 7;
    const int h     = bid & 1;
    const int tid   = threadIdx.x;
    const int tl    = tid % WEDGE_;
    const int rg    = tid / WEDGE_;
    const int wu    = wedge * WEDGE_ + tl;
    const int wol   = tl / UFT_;          // 0..7

    __shared__ float acc[C_][16][8];

    for (int i = tid; i < C_ * 16 * 8; i += BLK_)
        ((float*)acc)[i] = 0.0f;
    __syncthreads();

    const float lx = lt[b * 2 + 0];
    const float ly = lt[b * 2 + 1];
    const float* __restrict__ xb = x + (size_t)b * C_ * HI_ * WI_;

    #pragma unroll 1
    for (int k = 0; k < 4; ++k) {
        const int slot = rg + 4 * k;        // 0..15
        const int w    = h + 2 * slot;      // ho
        const int hu0  = w * UFR_;

        // ---- coordinates: packed a00 | dx1<<18 | dy1<<19 ----
        int   ap [UFR_];
        float wxv[UFR_], wyv[UFR_];
        #pragma unroll
        for (int rr = 0; rr < UFR_; ++rr) {
            const float2 g = *reinterpret_cast<const float2*>(
                grid + ((size_t)(hu0 + rr) * WUP_ + wu) * 2);
            float ix = ((g.x + lx + 1.0f) * (float)WI_ - 1.0f) * 0.5f;
            float iy = ((g.y + ly + 1.0f) * (float)HI_ - 1.0f) * 0.5f;
            ix = fminf(fmaxf(ix, 0.0f), (float)(WI_ - 1));
            iy = fminf(fmaxf(iy, 0.0f), (float)(HI_ - 1));
            const float x0f = floorf(ix);
            const float y0f = floorf(iy);
            const int x0 = (int)x0f;
            const int y0 = (int)y0f;
            const int dx1 = min(x0 + 1, WI_ - 1) - x0;   // 0/1
            const int dy1 = min(y0 + 1, HI_ - 1) - y0;   // 0/1
            ap [rr] = (y0 * WI_ + x0) | (dx1 << 18) | (dy1 << 19);
            wxv[rr] = ix - x0f;
            wyv[rr] = iy - y0f;
        }

        // ---- per-channel batched gathers (40 independent loads) ----
        float s[C_];
        #pragma unroll
        for (int c = 0; c < C_; ++c) {
            const float* __restrict__ xc = xb + (size_t)c * HI_ * WI_;
            float v00[UFR_], v01[UFR_], v10[UFR_], v11[UFR_];
            #pragma unroll
            for (int rr = 0; rr < UFR_; ++rr) {
                const int p   = ap[rr];
                const int A   = p & 0x3FFFF;
                const int dxo = (p >> 18) & 1;
                const int dyo = (p >> 10) & 512;   // bit19 -> +512
                v00[rr] = xc[A];
                v01[rr] = xc[A + dxo];
                v10[rr] = xc[A + dyo];
                v11[rr] = xc[A + dxo + dyo];
            }
            float a = 0.0f;
            #pragma unroll
            for (int rr = 0; rr < UFR_; ++rr) {
                const float w11 = wxv[rr] * wyv[rr];
                const float w10 = wyv[rr] - w11;
                const float w01 = wxv[rr] - w11;
                const float w00 = 1.0f - wxv[rr] - wyv[rr] + w11;
                a += v00[rr] * w00 + v01[rr] * w01 + v10[rr] * w10 + v11[rr] * w11;
            }
            s[c] = a;
        }

        atomicAdd(&acc[0][slot][wol], s[0]);
        atomicAdd(&acc[1][slot][wol], s[1]);
        atomicAdd(&acc[2][slot][wol], s[2]);
    }
    __syncthreads();

    for (int i = tid; i < C_ * 16 * 8; i += BLK_) {
        const int c    = i >> 7;
        const int rem  = i & 127;
        const int slot = rem >> 3;
        const int wl   = rem & 7;
        const int w    = h + 2 * slot;
        out[(((size_t)b * C_ + c) * HOUT_ + w) * WOUT_ + wedge * 8 + wl] =
            acc[c][slot][wl] * 0.01f;
    }
}

extern "C" void kernel_launch(void* const* d_in, const int* in_sizes, int n_in,
                              void* d_out, int out_size, void* d_ws, size_t ws_size,
                              hipStream_t stream)
{
    const float* x    = (const float*)d_in[0];
    const float* lt   = (const float*)d_in[1];
    const float* grid = (const float*)d_in[2];
    float* out        = (float*)d_out;

    retina_polar_kernel<<<dim3(B_ * 8 * 2), dim3(BLK_), 0, stream>>>(x, lt, grid, out);
}